// Round 2
// baseline (151.960 us; speedup 1.0000x reference)
//
#include <hip/hip_runtime.h>
#include <stdint.h>

#define NN 4096
#define MM 8192
#define DD 512

typedef __bf16 bf16x8 __attribute__((ext_vector_type(8)));
typedef __bf16 bf16x4 __attribute__((ext_vector_type(4)));
typedef float f32x4 __attribute__((ext_vector_type(4)));
typedef float f32x16 __attribute__((ext_vector_type(16)));

__device__ __forceinline__ void load_lds16(const void* g, void* l) {
  // async global -> LDS, 16B/lane; LDS dest must be wave-uniform base + lane*16.
  __builtin_amdgcn_global_load_lds(
      (const __attribute__((address_space(1))) unsigned int*)g,
      (__attribute__((address_space(3))) unsigned int*)l, 16, 0, 0);
}

// VALU-pipe partial reduction (R7/R8-verified correct): x += rot16(x, k).
template <int CTRL>
__device__ __forceinline__ float dpp_radd(float x) {
  int xi = __float_as_int(x);
  int mv = __builtin_amdgcn_update_dpp(xi, xi, CTRL, 0xF, 0xF, false);
  return x + __int_as_float(mv);
}
__device__ __forceinline__ float swz_add_xor16(float x) {
  int sv = __builtin_amdgcn_ds_swizzle(__float_as_int(x), 0x401F);
  return x + __int_as_float(sv);
}

// 4 rows per 256-thread block, one wave per row. (Unchanged, verified.)
__global__ __launch_bounds__(256) void convert_norm_kernel(
    const float* __restrict__ X, const float* __restrict__ SV,
    __bf16* __restrict__ Xb, __bf16* __restrict__ SVb,
    float* __restrict__ x2, float* __restrict__ sv2,
    float* __restrict__ out, const float* __restrict__ IC) {
  int wid = blockIdx.x * 4 + (threadIdx.x >> 6);
  int lane = threadIdx.x & 63;
  const float* src;
  __bf16* dst;
  float* nrm;
  if (wid < NN) {
    src = X + (size_t)wid * DD;
    dst = Xb + (size_t)wid * DD;
    nrm = x2 + wid;
    if (lane == 0) out[wid] = IC[0];
  } else {
    int r = wid - NN;
    src = SV + (size_t)r * DD;
    dst = SVb + (size_t)r * DD;
    nrm = sv2 + r;
  }
  const f32x4* s = (const f32x4*)src;
  f32x4 a = s[lane];       // elements 4l..4l+3
  f32x4 b = s[lane + 64];  // elements 256+4l..
  float sum = a.x * a.x + a.y * a.y + a.z * a.z + a.w * a.w +
              b.x * b.x + b.y * b.y + b.z * b.z + b.w * b.w;
  bf16x4 ca = {(__bf16)a.x, (__bf16)a.y, (__bf16)a.z, (__bf16)a.w};
  bf16x4 cb = {(__bf16)b.x, (__bf16)b.y, (__bf16)b.z, (__bf16)b.w};
  *(bf16x4*)(dst + 4 * lane) = ca;
  *(bf16x4*)(dst + 256 + 4 * lane) = cb;
#pragma unroll
  for (int m = 32; m >= 1; m >>= 1) sum += __shfl_xor(sum, m, 64);
  if (lane == 0) *nrm = sum;
}

// ---- fine-phase pipelined 256x256 GEMM ----
// Geometry identical to R1 (verified correct): 8 waves 2(n)x4(m), per-wave
// 128x64 = 4x2 of mfma_32x32x16; BK=32, 4-buffer LDS ring (128 KiB), stage
// tile t+3 during tile t, counted vmcnt(8) once per tile (=> t+1 landed at
// the tile-end barrier; R1 passed with these invariants).
// ONLY change vs R1: the coarse stage-all/compute-all tile body is split
// into 2 fine phases (m196/m201 lever). Each phase:
//   {6 ds_read_b128 | issue 2 global_load_lds} -> s_barrier ->
//   lgkmcnt(0)+sched_barrier(0) -> setprio(1) 8xMFMA setprio(0) -> s_barrier
// vmcnt(8) before the closing barrier of phase 1 only; tail drains 8->4->0.
template <bool STAGE, int VM, bool ENDBAR>
__device__ __forceinline__ void run_phase(
    f32x16 (&acc)[4][2], const bf16x8* __restrict__ Ab,
    const bf16x8* __restrict__ Bb, int aoff, int boff, int gs,
    const bf16x8* sg0, bf16x8* sl0, const bf16x8* sg1, bf16x8* sl1) {
  bf16x8 a0 = Ab[aoff + gs];
  bf16x8 a1 = Ab[aoff + 128 + gs];
  bf16x8 a2 = Ab[aoff + 256 + gs];
  bf16x8 a3 = Ab[aoff + 384 + gs];
  bf16x8 b0 = Bb[boff + gs];
  bf16x8 b1 = Bb[boff + 128 + gs];
  if (STAGE) {
    load_lds16(sg0, sl0);
    load_lds16(sg1, sl1);
  }
  __builtin_amdgcn_s_barrier();
  asm volatile("s_waitcnt lgkmcnt(0)" ::: "memory");
  __builtin_amdgcn_sched_barrier(0);
  __builtin_amdgcn_s_setprio(1);
  acc[0][0] = __builtin_amdgcn_mfma_f32_32x32x16_bf16(a0, b0, acc[0][0], 0, 0, 0);
  acc[0][1] = __builtin_amdgcn_mfma_f32_32x32x16_bf16(a0, b1, acc[0][1], 0, 0, 0);
  acc[1][0] = __builtin_amdgcn_mfma_f32_32x32x16_bf16(a1, b0, acc[1][0], 0, 0, 0);
  acc[1][1] = __builtin_amdgcn_mfma_f32_32x32x16_bf16(a1, b1, acc[1][1], 0, 0, 0);
  acc[2][0] = __builtin_amdgcn_mfma_f32_32x32x16_bf16(a2, b0, acc[2][0], 0, 0, 0);
  acc[2][1] = __builtin_amdgcn_mfma_f32_32x32x16_bf16(a2, b1, acc[2][1], 0, 0, 0);
  acc[3][0] = __builtin_amdgcn_mfma_f32_32x32x16_bf16(a3, b0, acc[3][0], 0, 0, 0);
  acc[3][1] = __builtin_amdgcn_mfma_f32_32x32x16_bf16(a3, b1, acc[3][1], 0, 0, 0);
  __builtin_amdgcn_s_setprio(0);
  if (VM == 8) asm volatile("s_waitcnt vmcnt(8)" ::: "memory");
  if (VM == 4) asm volatile("s_waitcnt vmcnt(4)" ::: "memory");
  if (VM == 0) asm volatile("s_waitcnt vmcnt(0)" ::: "memory");
  if (ENDBAR) __builtin_amdgcn_s_barrier();
}

__global__ __launch_bounds__(512, 2) void rbf_gemm_kernel(
    const bf16x8* __restrict__ Xb, const bf16x8* __restrict__ SVb,
    const float* __restrict__ x2, const float* __restrict__ sv2,
    const float* __restrict__ DC, const float* __restrict__ gamma_p,
    float* __restrict__ out) {
  __shared__ bf16x8 As[4096];  // 4 ring bufs x 256 rows x 4 granules = 64 KB
  __shared__ bf16x8 Bs[4096];  // 64 KB

  const int t = threadIdx.x;
  const int lane = t & 63;
  const int wave = t >> 6;
  const int l31 = lane & 31;
  const int lhi = lane >> 5;
  const int wave_n = wave & 1;   // 2 waves in n -> 128 rows each
  const int wave_m = wave >> 1;  // 4 waves in m -> 64 cols each
  const int n0 = blockIdx.x * 256;
  const int m0 = blockIdx.y * 256;

  // fragment-read swizzle (R1-verified conflict-free): granule g ^ ((row>>1)&3)
  const int rsw = (l31 >> 1) & 3;
  const int aoff = (wave_n * 128 + l31) * 4;
  const int boff = (wave_m * 64 + l31) * 4;
  const int g0 = lhi ^ rsw;        // ks = 0
  const int g1 = (2 + lhi) ^ rsw;  // ks = 1

  // staging source (pre-swizzled global address; R1-verified)
  const int row0 = t >> 2;
  const int gsw = (t & 3) ^ ((row0 >> 1) & 3);
  const bf16x8* srcA = Xb + (size_t)(n0 + row0) * 64 + gsw;
  const bf16x8* srcB = SVb + (size_t)(m0 + row0) * 64 + gsw;

  f32x16 acc[4][2];
#pragma unroll
  for (int i = 0; i < 4; ++i)
#pragma unroll
    for (int j = 0; j < 2; ++j)
#pragma unroll
      for (int r = 0; r < 16; ++r) acc[i][j][r] = 0.0f;

  // prologue: fill 3 ring slots (12 loads/wave), counted wait for tile 0 only.
#pragma unroll
  for (int tt = 0; tt < 3; ++tt) {
    load_lds16(srcA + tt * 4, As + tt * 1024 + t);
    load_lds16(srcA + tt * 4 + 8192, As + tt * 1024 + 512 + t);
    load_lds16(srcB + tt * 4, Bs + tt * 1024 + t);
    load_lds16(srcB + tt * 4 + 8192, Bs + tt * 1024 + 512 + t);
  }
  asm volatile("s_waitcnt vmcnt(8)" ::: "memory");  // tile 0 landed
  __builtin_amdgcn_s_barrier();

#pragma unroll 4
  for (int kt = 0; kt < 13; ++kt) {
    const int bc = kt & 3;
    const int bn = (kt + 3) & 3;
    const bf16x8* Ab = As + bc * 1024;
    const bf16x8* Bb = Bs + bc * 1024;
    const bf16x8* sa = srcA + (kt + 3) * 4;
    const bf16x8* sb = srcB + (kt + 3) * 4;
    // phase 0: frags(ks=0) + issue 2 A-half stages of tile kt+3
    run_phase<true, -1, true>(acc, Ab, Bb, aoff, boff, g0, sa,
                              As + bn * 1024 + t, sa + 8192,
                              As + bn * 1024 + 512 + t);
    // phase 1: frags(ks=1) + issue 2 B-half stages; vmcnt(8) => kt+1 landed
    run_phase<true, 8, true>(acc, Ab, Bb, aoff, boff, g1, sb,
                             Bs + bn * 1024 + t, sb + 8192,
                             Bs + bn * 1024 + 512 + t);
  }
  // tail: tiles 13,14,15 in bufs 1,2,3; drain 8 -> 4 -> 0.
  run_phase<false, -1, true>(acc, As + 1024, Bs + 1024, aoff, boff, g0,
                             nullptr, nullptr, nullptr, nullptr);
  run_phase<false, 4, true>(acc, As + 1024, Bs + 1024, aoff, boff, g1,
                            nullptr, nullptr, nullptr, nullptr);
  run_phase<false, -1, true>(acc, As + 2048, Bs + 2048, aoff, boff, g0,
                             nullptr, nullptr, nullptr, nullptr);
  run_phase<false, 0, true>(acc, As + 2048, Bs + 2048, aoff, boff, g1,
                            nullptr, nullptr, nullptr, nullptr);
  run_phase<false, -1, true>(acc, As + 3072, Bs + 3072, aoff, boff, g0,
                             nullptr, nullptr, nullptr, nullptr);
  run_phase<false, -1, false>(acc, As + 3072, Bs + 3072, aoff, boff, g1,
                              nullptr, nullptr, nullptr, nullptr);

  // ---- epilogue (byte-identical to R1-verified version) ----
  const float g = gamma_p[0];
  const float c2 = g * 1.4426950408889634f;  // gamma * log2(e)

  float sv2v[2], dcv[2];
  const int colb = m0 + wave_m * 64 + l31;
  sv2v[0] = sv2[colb];
  dcv[0] = DC[colb];
  sv2v[1] = sv2[colb + 32];
  dcv[1] = DC[colb + 32];

#pragma unroll
  for (int i = 0; i < 4; ++i) {
    // C row = rowb + 8*g4 + r2, where reg = g4*4 + r2
    const int rowb = n0 + wave_n * 128 + i * 32 + 4 * lhi;
    float val[16];
#pragma unroll
    for (int g4 = 0; g4 < 4; ++g4) {
      f32x4 xv = *(const f32x4*)(x2 + rowb + 8 * g4);
#pragma unroll
      for (int r2 = 0; r2 < 4; ++r2) {
        const int reg = g4 * 4 + r2;
        float v = 0.0f;
#pragma unroll
        for (int j = 0; j < 2; ++j) {
          float d2 = xv[r2] + sv2v[j] - 2.0f * acc[i][j][reg];
          d2 = fmaxf(d2, 0.0f);
          v += exp2f(-c2 * d2) * dcv[j];
        }
        val[reg] = v;
      }
    }
    // reduce over 32 column-lanes: 4 DPP row-rotations (VALU pipe) + one
    // ds_swizzle xor16 (R7/R8-verified).
#pragma unroll
    for (int reg = 0; reg < 16; ++reg) {
      float v = val[reg];
      v = dpp_radd<0x121>(v);  // row_ror:1
      v = dpp_radd<0x122>(v);  // row_ror:2
      v = dpp_radd<0x124>(v);  // row_ror:4
      v = dpp_radd<0x128>(v);  // row_ror:8
      val[reg] = swz_add_xor16(v);
    }
    if (l31 == 0) {
#pragma unroll
      for (int g4 = 0; g4 < 4; ++g4)
#pragma unroll
        for (int r2 = 0; r2 < 4; ++r2)
          atomicAdd(&out[rowb + 8 * g4 + r2], val[g4 * 4 + r2]);
    }
  }
}

extern "C" void kernel_launch(void* const* d_in, const int* in_sizes, int n_in,
                              void* d_out, int out_size, void* d_ws, size_t ws_size,
                              hipStream_t stream) {
  const float* X = (const float*)d_in[0];
  const float* SV = (const float*)d_in[1];
  const float* DC = (const float*)d_in[2];
  const float* IC = (const float*)d_in[3];
  const float* gamma = (const float*)d_in[4];
  float* out = (float*)d_out;

  char* ws = (char*)d_ws;
  __bf16* Xb = (__bf16*)ws;                                   // 4 MB
  __bf16* SVb = (__bf16*)(ws + (size_t)NN * DD * 2);          // 8 MB
  float* x2 = (float*)(ws + (size_t)(NN + MM) * DD * 2);      // 16 KB
  float* sv2 = x2 + NN;                                       // 32 KB

  convert_norm_kernel<<<(NN + MM) / 4, 256, 0, stream>>>(X, SV, Xb, SVb, x2, sv2, out, IC);
  dim3 grid(NN / 256, MM / 256);
  rbf_gemm_kernel<<<grid, 512, 0, stream>>>((const bf16x8*)Xb, (const bf16x8*)SVb,
                                            x2, sv2, DC, gamma, out);
}

// Round 3
// 132.075 us; speedup vs baseline: 1.1506x; 1.1506x over previous
//
#include <hip/hip_runtime.h>
#include <stdint.h>

#define NN 4096
#define MM 8192
#define DD 512
#define KT 8  // 512 / BK, BK = 64

typedef __bf16 bf16x8 __attribute__((ext_vector_type(8)));
typedef __bf16 bf16x4 __attribute__((ext_vector_type(4)));
typedef float f32x4 __attribute__((ext_vector_type(4)));
typedef float f32x16 __attribute__((ext_vector_type(16)));

__device__ __forceinline__ void load_lds16(const void* g, void* l) {
  // async global -> LDS, 16B/lane; LDS dest must be wave-uniform base + lane*16.
  __builtin_amdgcn_global_load_lds(
      (const __attribute__((address_space(1))) unsigned int*)g,
      (__attribute__((address_space(3))) unsigned int*)l, 16, 0, 0);
}

// VALU-pipe partial reduction (R7/R8-verified correct): x += rot16(x, k).
template <int CTRL>
__device__ __forceinline__ float dpp_radd(float x) {
  int xi = __float_as_int(x);
  int mv = __builtin_amdgcn_update_dpp(xi, xi, CTRL, 0xF, 0xF, false);
  return x + __int_as_float(mv);
}
__device__ __forceinline__ float swz_add_xor16(float x) {
  int sv = __builtin_amdgcn_ds_swizzle(__float_as_int(x), 0x401F);
  return x + __int_as_float(sv);
}

// 4 rows per 256-thread block, one wave per row. Fully-coalesced f32x4 loads,
// bf16x4 stores, exact fp32 row-norm, and out[]=IC init folded in.
__global__ __launch_bounds__(256) void convert_norm_kernel(
    const float* __restrict__ X, const float* __restrict__ SV,
    __bf16* __restrict__ Xb, __bf16* __restrict__ SVb,
    float* __restrict__ x2, float* __restrict__ sv2,
    float* __restrict__ out, const float* __restrict__ IC) {
  int wid = blockIdx.x * 4 + (threadIdx.x >> 6);
  int lane = threadIdx.x & 63;
  const float* src;
  __bf16* dst;
  float* nrm;
  if (wid < NN) {
    src = X + (size_t)wid * DD;
    dst = Xb + (size_t)wid * DD;
    nrm = x2 + wid;
    if (lane == 0) out[wid] = IC[0];
  } else {
    int r = wid - NN;
    src = SV + (size_t)r * DD;
    dst = SVb + (size_t)r * DD;
    nrm = sv2 + r;
  }
  const f32x4* s = (const f32x4*)src;
  f32x4 a = s[lane];       // elements 4l..4l+3
  f32x4 b = s[lane + 64];  // elements 256+4l..
  float sum = a.x * a.x + a.y * a.y + a.z * a.z + a.w * a.w +
              b.x * b.x + b.y * b.y + b.z * b.z + b.w * b.w;
  bf16x4 ca = {(__bf16)a.x, (__bf16)a.y, (__bf16)a.z, (__bf16)a.w};
  bf16x4 cb = {(__bf16)b.x, (__bf16)b.y, (__bf16)b.z, (__bf16)b.w};
  *(bf16x4*)(dst + 4 * lane) = ca;
  *(bf16x4*)(dst + 256 + 4 * lane) = cb;
#pragma unroll
  for (int m = 32; m >= 1; m >>= 1) sum += __shfl_xor(sum, m, 64);
  if (lane == 0) *nrm = sum;
}

// R0 champion structure VERBATIM (59.3 us measured): 128x128 tile, BK=64,
// 4 waves (2x2), each wave 64x64 via 2x2 of mfma_f32_32x32x16_bf16, single
// 32 KB LDS buffer -> 4 blocks/CU; cross-block wave overlap hides staging
// (the mechanism R1/R2's 1-block/CU deep pipeline lacked — both measured
// 85 us). ONLY change vs R0: bijective 2D XCD-chunked block swizzle so each
// XCD's staging working set is ~4 MB (16 n-panels of Xb + 16 m-panels of
// SVb = 2+2 MB), fitting its private L2. Targets the measured 3x HBM
// re-fetch (FETCH 35.4 MB vs 12 MB unique).
__global__ __launch_bounds__(256, 4) void rbf_gemm_kernel(
    const bf16x8* __restrict__ Xb, const bf16x8* __restrict__ SVb,
    const float* __restrict__ x2, const float* __restrict__ sv2,
    const float* __restrict__ DC, const float* __restrict__ gamma_p,
    float* __restrict__ out) {
  __shared__ bf16x8 As[1024];  // 16 KB
  __shared__ bf16x8 Bs[1024];  // 16 KB

  const int t = threadIdx.x;
  const int lane = t & 63;
  const int wave = t >> 6;

  // ---- XCD-chunked bijective swizzle (only change vs R0) ----
  // linear id (x-fastest dispatch), 2048 blocks, 8 XCDs.
  // xcd = id&7 -> chunk (cn,cm) in a 2x4 grid of 16x16-tile chunks;
  // idx = id>>3 indexes n-fastest within the chunk. Bijective by construction.
  const int id = blockIdx.y * gridDim.x + blockIdx.x;
  const int xcd = id & 7;
  const int idx = id >> 3;
  const int bn = (xcd & 1) * 16 + (idx & 15);
  const int bm = (xcd >> 1) * 16 + (idx >> 4);
  const int n0 = bn * 128;
  const int m0 = bm * 128;

  const int wave_m = wave & 1;   // m-dir of C
  const int wave_n = wave >> 1;  // n-dir of C
  const int l31 = lane & 31;
  const int lhi = lane >> 5;

  // staging decomposition: chunk c_it = it*256 + t
  const int srow = t >> 3;            // row contribution for it=0 (rows 0..31)
  const int sslot = t & 7;

  f32x16 acc[2][2];
#pragma unroll
  for (int i = 0; i < 2; ++i)
#pragma unroll
    for (int j = 0; j < 2; ++j)
#pragma unroll
      for (int r = 0; r < 16; ++r) acc[i][j][r] = 0.0f;

  for (int kt = 0; kt < KT; ++kt) {
    // ---- cooperative staging: 4 instrs A + 4 instrs B per thread ----
#pragma unroll
    for (int it = 0; it < 4; ++it) {
      const int c = it * 256 + t;
      const int row = it * 32 + srow;
      const int kg = sslot ^ (row & 7);
      load_lds16(Xb + (size_t)(n0 + row) * 64 + kt * 8 + kg, &As[c]);
      load_lds16(SVb + (size_t)(m0 + row) * 64 + kt * 8 + kg, &Bs[c]);
    }
    __syncthreads();
    // ---- compute ----
#pragma unroll
    for (int ks = 0; ks < 4; ++ks) {
      const int kc = ks * 2 + lhi;        // k-chunk 0..7
      const int sw = kc ^ (l31 & 7);
      const int ra = (wave_n * 64 + l31) * 8;
      const int rb = (wave_m * 64 + l31) * 8;
      bf16x8 af0 = As[ra + sw];
      bf16x8 af1 = As[ra + 256 + sw];  // +32 rows
      bf16x8 bf0 = Bs[rb + sw];
      bf16x8 bf1 = Bs[rb + 256 + sw];
      acc[0][0] = __builtin_amdgcn_mfma_f32_32x32x16_bf16(af0, bf0, acc[0][0], 0, 0, 0);
      acc[0][1] = __builtin_amdgcn_mfma_f32_32x32x16_bf16(af0, bf1, acc[0][1], 0, 0, 0);
      acc[1][0] = __builtin_amdgcn_mfma_f32_32x32x16_bf16(af1, bf0, acc[1][0], 0, 0, 0);
      acc[1][1] = __builtin_amdgcn_mfma_f32_32x32x16_bf16(af1, bf1, acc[1][1], 0, 0, 0);
    }
    __syncthreads();
  }

  // ---- epilogue (no barriers) ----
  const float g = gamma_p[0];
  const float c2 = g * 1.4426950408889634f;  // gamma * log2(e)

  float sv2v[2], dcv[2];
  const int colb = m0 + wave_m * 64 + l31;
  sv2v[0] = sv2[colb];
  dcv[0] = DC[colb];
  sv2v[1] = sv2[colb + 32];
  dcv[1] = DC[colb + 32];

#pragma unroll
  for (int i = 0; i < 2; ++i) {
    // C row = rowb + 8*g4 + r2, where reg = g4*4 + r2
    const int rowb = n0 + wave_n * 64 + i * 32 + 4 * lhi;
    float val[16];
#pragma unroll
    for (int g4 = 0; g4 < 4; ++g4) {
      f32x4 xv = *(const f32x4*)(x2 + rowb + 8 * g4);
#pragma unroll
      for (int r2 = 0; r2 < 4; ++r2) {
        const int reg = g4 * 4 + r2;
        float v = 0.0f;
#pragma unroll
        for (int j = 0; j < 2; ++j) {
          float d2 = xv[r2] + sv2v[j] - 2.0f * acc[i][j][reg];
          d2 = fmaxf(d2, 0.0f);
          v += exp2f(-c2 * d2) * dcv[j];
        }
        val[reg] = v;
      }
    }
    // reduce over 32 column-lanes: 4 DPP row-rotations (VALU pipe) + one
    // ds_swizzle xor16 (R7/R8-verified).
#pragma unroll
    for (int reg = 0; reg < 16; ++reg) {
      float v = val[reg];
      v = dpp_radd<0x121>(v);  // row_ror:1
      v = dpp_radd<0x122>(v);  // row_ror:2
      v = dpp_radd<0x124>(v);  // row_ror:4
      v = dpp_radd<0x128>(v);  // row_ror:8
      val[reg] = swz_add_xor16(v);
    }
    if (l31 == 0) {
#pragma unroll
      for (int g4 = 0; g4 < 4; ++g4)
#pragma unroll
        for (int r2 = 0; r2 < 4; ++r2)
          atomicAdd(&out[rowb + 8 * g4 + r2], val[g4 * 4 + r2]);
    }
  }
}

extern "C" void kernel_launch(void* const* d_in, const int* in_sizes, int n_in,
                              void* d_out, int out_size, void* d_ws, size_t ws_size,
                              hipStream_t stream) {
  const float* X = (const float*)d_in[0];
  const float* SV = (const float*)d_in[1];
  const float* DC = (const float*)d_in[2];
  const float* IC = (const float*)d_in[3];
  const float* gamma = (const float*)d_in[4];
  float* out = (float*)d_out;

  char* ws = (char*)d_ws;
  __bf16* Xb = (__bf16*)ws;                                   // 4 MB
  __bf16* SVb = (__bf16*)(ws + (size_t)NN * DD * 2);          // 8 MB
  float* x2 = (float*)(ws + (size_t)(NN + MM) * DD * 2);      // 16 KB
  float* sv2 = x2 + NN;                                       // 32 KB

  convert_norm_kernel<<<(NN + MM) / 4, 256, 0, stream>>>(X, SV, Xb, SVb, x2, sv2, out, IC);
  dim3 grid(NN / 128, MM / 128);
  rbf_gemm_kernel<<<grid, 256, 0, stream>>>((const bf16x8*)Xb, (const bf16x8*)SVb,
                                            x2, sv2, DC, gamma, out);
}